// Round 11
// baseline (4167.086 us; speedup 1.0000x reference)
//
#include <hip/hip_runtime.h>
#include <hip/hip_bf16.h>

#define BATCH 128
#define SEQ   1024
#define INDIM 256
#define HID   1024
#define NGATE 4096   // 4*HID
#define KTOT  1280   // INDIM + HID
#define OUTD  256
#define NBG   4      // batch groups
#define ROWS  32     // batch rows per group
#define NSL   64     // WGs per group
#define JCOLS 16     // h-cols per WG (x4 gates = 64 gate-cols)
#define XKK   8      // x k-steps of 32
#define HKK   32     // h k-steps of 32

typedef __attribute__((ext_vector_type(8))) short s16x8;
typedef __attribute__((ext_vector_type(4))) float f32x4;

__device__ __forceinline__ unsigned short f2bf(float f) {
    unsigned int u = __float_as_uint(f);
    u += 0x7FFFu + ((u >> 16) & 1u);
    return (unsigned short)(u >> 16);
}
__device__ __forceinline__ float sigmoidf_(float x) {
    return 1.0f / (1.0f + __expf(-x));
}
__device__ __forceinline__ float tanhf_(float x) {
    return 1.0f - 2.0f / (1.0f + __expf(2.0f * x));
}

// ---------------------------------------------------------------------------
// Prep 1: WT[n][k] bf16 (transposed, concatenated [Wx;Wh])
// ---------------------------------------------------------------------------
__global__ __launch_bounds__(256) void prep_wt(const float* __restrict__ Wx,
                                               const float* __restrict__ Wh,
                                               unsigned short* __restrict__ WT) {
    __shared__ float tile[64][65];
    int k0 = blockIdx.x * 64;
    int n0 = blockIdx.y * 64;
    for (int idx = threadIdx.x; idx < 64 * 64; idx += 256) {
        int kk = idx >> 6, nn = idx & 63;
        int k = k0 + kk;
        float v = (k < INDIM) ? Wx[(size_t)k * NGATE + (n0 + nn)]
                              : Wh[(size_t)(k - INDIM) * NGATE + (n0 + nn)];
        tile[kk][nn] = v;
    }
    __syncthreads();
    for (int idx = threadIdx.x; idx < 64 * 64; idx += 256) {
        int nn = idx >> 6, kk = idx & 63;
        WT[(size_t)(n0 + nn) * KTOT + (k0 + kk)] = f2bf(tile[kk][nn]);
    }
}

// ---------------------------------------------------------------------------
// Prep 2: x fp32 -> bf16, zero h0, zero per-WG flags (256 x 64 uints)
// ---------------------------------------------------------------------------
__global__ __launch_bounds__(256) void prep_x(const float* __restrict__ x,
                                              unsigned short* __restrict__ xb,
                                              unsigned short* __restrict__ h0,
                                              unsigned int* __restrict__ flags) {
    int gid = blockIdx.x * blockDim.x + threadIdx.x;
    int stride = gridDim.x * blockDim.x;
    const int N4 = BATCH * SEQ * INDIM / 4;
    const float4* xv = reinterpret_cast<const float4*>(x);
    uint2* xo = reinterpret_cast<uint2*>(xb);
    for (int i = gid; i < N4; i += stride) {
        float4 v = xv[i];
        uint2 o;
        o.x = (unsigned)f2bf(v.x) | ((unsigned)f2bf(v.y) << 16);
        o.y = (unsigned)f2bf(v.z) | ((unsigned)f2bf(v.w) << 16);
        xo[i] = o;
    }
    const int NH = BATCH * HID;
    for (int i = gid; i < NH; i += stride) h0[i] = 0;
    for (int i = gid; i < 16384; i += stride) flags[i] = 0;
}

// ---------------------------------------------------------------------------
// Persistent LSTM.  256 WGs x 256 thr (4 waves), launch_bounds(256,1).
// WG = (g = blk>>6, i = blk&63): rows g*32..+32, h-cols i*16..+16, 4 gates.
//   -> per-XCD (blk&7 round-robin) WT slices = 8 x 160 KB = 1.28 MB, L2-fits.
// Wave = (np = w&1 -> gates {2np,2np+1}, kh = w>>1 -> K-half):
//   B = 40 frags (x: 4 ks, h: 16 ks; both 16-col tiles) = 160 AGPRs, pinned.
//   Arch VGPR class (<=256) and AGPR class (<=256) BOTH fit for the first
//   time (rounds 3-10 all demanded >256 of one class -> remat from WT).
// MFMA 16x16x32, proven p_l-swizzled LDS slices [16r][32k].
// Sync: r3-proven per-WG flags + 4 barriers + agent-scope atomics.
// ---------------------------------------------------------------------------
__global__ __launch_bounds__(256, 1) void lstm_persist(
    const unsigned short* __restrict__ xb,   // [B][S][INDIM] bf16
    const unsigned short* __restrict__ WT,   // [NGATE][KTOT] bf16
    unsigned short* __restrict__ h0,         // [B][HID] bf16 (zeroed)
    unsigned short* __restrict__ h1,         // [B][HID] bf16
    unsigned int* __restrict__ flags,        // 256 WG x 64 uints (zeroed)
    const float* __restrict__ bias) {        // [NGATE]

    __shared__ unsigned short xbuf[2][16 * 512];  // 2 x 16 KB  [s=ks*2+mt][512]
    __shared__ unsigned short hbuf[64 * 512];     // 64 KB      [s=hks*2+mt][512]
    __shared__ float gex2[2][32][68];             // 17.4 KB    [kh][row][g'*17+col]

    const int tid  = threadIdx.x;
    const int wave = tid >> 6, lane = tid & 63;
    const int lr = lane & 15, kq = lane >> 4;
    const int g  = blockIdx.x >> 6;   // 0..3 batch group
    const int i  = blockIdx.x & 63;   // 0..63 column slice
    const int b0 = g * ROWS;
    const int j0 = i * JCOLS;
    const int np = wave & 1;          // gate pair {2np, 2np+1}
    const int kh = wave >> 1;         // K-half

    // ---- B fragments: idx 0..3 = x-ks (kh*4+idx), idx 4..19 = h-ks (kh*16+idx-4)
    s16x8 bA[20], bB[20];   // gate 2np, gate 2np+1 (cols j0..j0+15 each)
    {
        const unsigned short* baseA =
            WT + ((size_t)((2 * np) * HID + j0 + lr)) * KTOT + kq * 8;
        const unsigned short* baseB = baseA + (size_t)HID * KTOT;
#pragma unroll
        for (int idx = 0; idx < 4; idx++) {
            int off = (kh * 4 + idx) * 32;
            bA[idx] = *reinterpret_cast<const s16x8*>(baseA + off);
            bB[idx] = *reinterpret_cast<const s16x8*>(baseB + off);
        }
#pragma unroll
        for (int idx = 4; idx < 20; idx++) {
            int off = INDIM + (kh * 16 + (idx - 4)) * 32;
            bA[idx] = *reinterpret_cast<const s16x8*>(baseA + off);
            bB[idx] = *reinterpret_cast<const s16x8*>(baseB + off);
        }
    }
    // ---- pin into the AGPR class (160 regs <= 256-class cap) ----
#pragma unroll
    for (int q = 0; q < 20; q++) {
        asm volatile("" : "+a"(bA[q]));
        asm volatile("" : "+a"(bB[q]));
    }

    // ---- epilogue constants: 256 thr x 2 cells (rows tid>>4 and +16) ----
    const int hcol = tid & 15, row0 = tid >> 4, row1 = row0 + 16;
    const int j = j0 + hcol;
    const float bf_ = bias[0 * HID + j], bi_ = bias[1 * HID + j],
                bg_ = bias[2 * HID + j], bo_ = bias[3 * HID + j];
    float c0 = 0.f, c1 = 0.f;

    // ---- x staging: wave (np,kh) stages slices s = (2r+kh)*2 + np, r=0..3 ----
    const int srow4 = lane >> 2;
    const int skq = ((lane & 3) - ((lane >> 3) & 3)) & 3;
    const unsigned short* xsrc =
        xb + (size_t)(b0 + np * 16 + srow4) * SEQ * INDIM + skq * 8;
    // MFMA A-read slot
    const int p_l = lr * 4 + ((kq + (lr >> 1)) & 3);

    unsigned int* myflag = flags + (size_t)(g * NSL + i) * 64;

    // ---- prologue: stage x for t=0 ----
#pragma unroll
    for (int r = 0; r < 4; r++) {
        int ks = 2 * r + kh;
        __builtin_amdgcn_global_load_lds(
            (const __attribute__((address_space(1))) void*)(xsrc + (size_t)ks * 32),
            (__attribute__((address_space(3))) void*)(&xbuf[0][(ks * 2 + np) * 512]),
            16, 0, 0);
    }
    __syncthreads();

    for (int t = 0; t < SEQ; t++) {
        const unsigned short* hin = (t & 1) ? h1 : h0;
        unsigned short* hout      = (t & 1) ? h0 : h1;
        const int par = t & 1;

        // ---- x-part MFMA (idx 0..3) ----
        f32x4 a00 = {0.f, 0.f, 0.f, 0.f}, a01 = {0.f, 0.f, 0.f, 0.f};
        f32x4 a10 = {0.f, 0.f, 0.f, 0.f}, a11 = {0.f, 0.f, 0.f, 0.f};
        {
            const unsigned short* axb = &xbuf[par][p_l * 8];
#pragma unroll
            for (int idx = 0; idx < 4; idx++) {
                int xks = kh * 4 + idx;
                s16x8 am0 = *reinterpret_cast<const s16x8*>(axb + (xks * 2 + 0) * 512);
                s16x8 am1 = *reinterpret_cast<const s16x8*>(axb + (xks * 2 + 1) * 512);
                a00 = __builtin_amdgcn_mfma_f32_16x16x32_bf16(am0, bA[idx], a00, 0, 0, 0);
                a01 = __builtin_amdgcn_mfma_f32_16x16x32_bf16(am0, bB[idx], a01, 0, 0, 0);
                a10 = __builtin_amdgcn_mfma_f32_16x16x32_bf16(am1, bA[idx], a10, 0, 0, 0);
                a11 = __builtin_amdgcn_mfma_f32_16x16x32_bf16(am1, bB[idx], a11, 0, 0, 0);
            }
        }

        // ---- fire-and-forget: stage x for t+1 ----
        if (t + 1 < SEQ) {
#pragma unroll
            for (int r = 0; r < 4; r++) {
                int ks = 2 * r + kh;
                __builtin_amdgcn_global_load_lds(
                    (const __attribute__((address_space(1))) void*)(xsrc + (size_t)(t + 1) * INDIM + ks * 32),
                    (__attribute__((address_space(3))) void*)(&xbuf[par ^ 1][(ks * 2 + np) * 512]),
                    16, 0, 0);
            }
        }

        // ---- wait for all 64 producers of this group ----
        if (tid < 64) {
            const unsigned int* fp = flags + (size_t)(g * NSL + tid) * 64;
            while (__hip_atomic_load(fp, __ATOMIC_RELAXED,
                                     __HIP_MEMORY_SCOPE_AGENT) < (unsigned)t) {
                __builtin_amdgcn_s_sleep(1);
            }
        }
        asm volatile("" ::: "memory");
        __syncthreads();   // B1

        // ---- h (32 rows x 1024) -> hbuf, 2 rounds of 16 x 8B ----
        {
            const unsigned long long* hin_u = (const unsigned long long*)hin;
#pragma unroll
            for (int half = 0; half < 2; half++) {
                unsigned long long hv[16];
#pragma unroll
                for (int q = 0; q < 16; q++) {
                    int v = tid + 256 * (half * 16 + q);
                    int hks = v >> 8, w8 = v & 255, row = w8 >> 3, k8 = w8 & 7;
                    hv[q] = __hip_atomic_load(
                        hin_u + (size_t)(b0 + row) * 256 + hks * 8 + k8,
                        __ATOMIC_RELAXED, __HIP_MEMORY_SCOPE_AGENT);
                }
#pragma unroll
                for (int q = 0; q < 16; q++) {
                    int v = tid + 256 * (half * 16 + q);
                    int hks = v >> 8, w8 = v & 255, row = w8 >> 3, k8 = w8 & 7;
                    int r16 = row & 15, mt = row >> 4, kq2 = k8 >> 1;
                    int p = r16 * 4 + ((kq2 + (r16 >> 1)) & 3);
                    *(unsigned long long*)((char*)hbuf + (hks * 2 + mt) * 1024 +
                                           p * 16 + (k8 & 1) * 8) = hv[q];
                }
            }
        }
        __syncthreads();   // B2: hbuf ready

        // ---- h-part MFMA (idx 4..19) ----
        {
            const unsigned short* ahb = &hbuf[p_l * 8];
#pragma unroll
            for (int idx = 4; idx < 20; idx++) {
                int hks = kh * 16 + (idx - 4);
                s16x8 am0 = *reinterpret_cast<const s16x8*>(ahb + (hks * 2 + 0) * 512);
                s16x8 am1 = *reinterpret_cast<const s16x8*>(ahb + (hks * 2 + 1) * 512);
                a00 = __builtin_amdgcn_mfma_f32_16x16x32_bf16(am0, bA[idx], a00, 0, 0, 0);
                a01 = __builtin_amdgcn_mfma_f32_16x16x32_bf16(am0, bB[idx], a01, 0, 0, 0);
                a10 = __builtin_amdgcn_mfma_f32_16x16x32_bf16(am1, bA[idx], a10, 0, 0, 0);
                a11 = __builtin_amdgcn_mfma_f32_16x16x32_bf16(am1, bB[idx], a11, 0, 0, 0);
            }
        }

        // ---- K-partials -> gex2 (C/D: col=lane&15, row=(lane>>4)*4+r) ----
        {
            float* gx = &gex2[kh][0][0];
            const int ci0 = (np * 2 + 0) * 17 + lr;
            const int ci1 = (np * 2 + 1) * 17 + lr;
#pragma unroll
            for (int r = 0; r < 4; r++) {
                int row = kq * 4 + r;
                gx[row * 68 + ci0]        = a00[r];
                gx[row * 68 + ci1]        = a01[r];
                gx[(row + 16) * 68 + ci0] = a10[r];
                gx[(row + 16) * 68 + ci1] = a11[r];
            }
        }
        __syncthreads();   // B3: gex2 ready

        // ---- activations + c update + h stores (2 cells/thread) ----
        {
            float gf = gex2[0][row0][0 * 17 + hcol] + gex2[1][row0][0 * 17 + hcol] + bf_;
            float gi = gex2[0][row0][1 * 17 + hcol] + gex2[1][row0][1 * 17 + hcol] + bi_;
            float gg = gex2[0][row0][2 * 17 + hcol] + gex2[1][row0][2 * 17 + hcol] + bg_;
            float go = gex2[0][row0][3 * 17 + hcol] + gex2[1][row0][3 * 17 + hcol] + bo_;
            float ff = sigmoidf_(gf), ii = sigmoidf_(gi);
            float g2 = tanhf_(gg), oo = sigmoidf_(go);
            c0 = ff * c0 + ii * g2;
            __hip_atomic_store(hout + (size_t)(b0 + row0) * HID + j,
                               f2bf(oo * tanhf_(c0)),
                               __ATOMIC_RELAXED, __HIP_MEMORY_SCOPE_AGENT);
        }
        {
            float gf = gex2[0][row1][0 * 17 + hcol] + gex2[1][row1][0 * 17 + hcol] + bf_;
            float gi = gex2[0][row1][1 * 17 + hcol] + gex2[1][row1][1 * 17 + hcol] + bi_;
            float gg = gex2[0][row1][2 * 17 + hcol] + gex2[1][row1][2 * 17 + hcol] + bg_;
            float go = gex2[0][row1][3 * 17 + hcol] + gex2[1][row1][3 * 17 + hcol] + bo_;
            float ff = sigmoidf_(gf), ii = sigmoidf_(gi);
            float g2 = tanhf_(gg), oo = sigmoidf_(go);
            c1 = ff * c1 + ii * g2;
            __hip_atomic_store(hout + (size_t)(b0 + row1) * HID + j,
                               f2bf(oo * tanhf_(c1)),
                               __ATOMIC_RELAXED, __HIP_MEMORY_SCOPE_AGENT);
        }

        __syncthreads();   // B4: all stores drained, gex2/hbuf reusable
        asm volatile("" ::: "memory");
        if (tid == 0) {
            __hip_atomic_store(myflag, (unsigned)(t + 1),
                               __ATOMIC_RELAXED, __HIP_MEMORY_SCOPE_AGENT);
        }
    }
}

// ---------------------------------------------------------------------------
// Final FC
// ---------------------------------------------------------------------------
__global__ __launch_bounds__(256) void final_fc(const unsigned short* __restrict__ h,
                                                const float* __restrict__ Wfc,
                                                const float* __restrict__ bfc,
                                                float* __restrict__ out) {
    int b = blockIdx.x;
    int o = threadIdx.x;
    const unsigned short* hr = h + (size_t)b * HID;
    float acc = bfc[o];
#pragma unroll 8
    for (int k = 0; k < HID; k++) {
        acc += __uint_as_float(((unsigned)hr[k]) << 16) * Wfc[(size_t)k * OUTD + o];
    }
    out[(size_t)b * OUTD + o] = acc;
}

// ---------------------------------------------------------------------------
extern "C" void kernel_launch(void* const* d_in, const int* in_sizes, int n_in,
                              void* d_out, int out_size, void* d_ws, size_t ws_size,
                              hipStream_t stream) {
    const float* x    = (const float*)d_in[0];
    const float* Wx   = (const float*)d_in[1];
    const float* Wh   = (const float*)d_in[2];
    const float* bias = (const float*)d_in[3];
    const float* Wfc  = (const float*)d_in[4];
    const float* bfc  = (const float*)d_in[5];
    float* out = (float*)d_out;

    char* ws = (char*)d_ws;
    // ws layout (bytes):
    //   WT    : 4096*1280*2    = 10,485,760  @ 0
    //   xb    : 128*1024*256*2 = 67,108,864  @ 10,485,760
    //   h0    : 128*1024*2     =    262,144  @ 77,594,624
    //   h1    : 128*1024*2     =    262,144  @ 77,856,768
    //   flags : 16384*4        =     65,536  @ 78,118,912
    unsigned short* WT  = (unsigned short*)(ws);
    unsigned short* xb  = (unsigned short*)(ws + 10485760);
    unsigned short* h0  = (unsigned short*)(ws + 77594624);
    unsigned short* h1  = (unsigned short*)(ws + 77856768);
    unsigned int* flags = (unsigned int*)(ws + 78118912);

    hipLaunchKernelGGL(prep_wt, dim3(KTOT / 64, NGATE / 64), dim3(256), 0, stream,
                       Wx, Wh, WT);
    hipLaunchKernelGGL(prep_x, dim3(1024), dim3(256), 0, stream, x, xb, h0, flags);

    hipLaunchKernelGGL(lstm_persist, dim3(256), dim3(256), 0, stream,
                       xb, WT, h0, h1, flags, bias);

    // 1024 steps -> final h lands in h0
    hipLaunchKernelGGL(final_fc, dim3(128), dim3(256), 0, stream, h0, Wfc, bfc, out);
}